// Round 1
// baseline (2116.956 us; speedup 1.0000x reference)
//
#include <hip/hip_runtime.h>
#include <cstddef>

#define EPSV 1e-5f

constexpr int Bv = 64, Sv = 4, BSv = 256;
constexpr int H1 = 28, W1 = 28, HW1 = 784;
constexpr int C1 = 64, C2 = 128, C3 = 256;

// ---------------- conv1 (1->64) + relu ----------------
__global__ void conv1_relu_k(const float* __restrict__ x, const float* __restrict__ w,
                             const float* __restrict__ b, float* __restrict__ out) {
    int idx = blockIdx.x * 256 + threadIdx.x;  // (bs, c, p)
    if (idx >= BSv * C1 * HW1) return;
    int p = idx % HW1;
    int c = (idx / HW1) % C1;
    int bs = idx / (HW1 * C1);
    int h = p / W1, wx = p % W1;
    const float* xi = x + (size_t)bs * HW1;
    float acc = b[c];
#pragma unroll
    for (int ki = 0; ki < 3; ki++) {
        int y = h - 1 + ki;
        if (y < 0 || y >= H1) continue;
#pragma unroll
        for (int kj = 0; kj < 3; kj++) {
            int xx = wx - 1 + kj;
            if (xx < 0 || xx >= W1) continue;
            acc += xi[y * W1 + xx] * w[c * 9 + ki * 3 + kj];
        }
    }
    out[idx] = fmaxf(acc, 0.f);
}

// ---------------- BN stats: one block per (c,s); writes fused scale/shift ----------------
template <int C, int HWs>
__global__ void bn_stats_k(const float* __restrict__ in, const float* __restrict__ g,
                           const float* __restrict__ be, int mode,
                           float* __restrict__ scale, float* __restrict__ shift) {
    int cs = blockIdx.x;  // c*Sv + s
    int c = cs / Sv, s = cs % Sv;
    int tid = threadIdx.x;
    float sum = 0.f, sq = 0.f;
    const int n = Bv * HWs;
    for (int i = tid; i < n; i += 256) {
        int b = i / HWs, p = i % HWs;
        float v = in[((size_t)(b * Sv + s) * C + c) * HWs + p];
        sum += v;
        sq += v * v;
    }
    __shared__ float rs[256], rq[256];
    rs[tid] = sum; rq[tid] = sq;
    __syncthreads();
    for (int off = 128; off > 0; off >>= 1) {
        if (tid < off) { rs[tid] += rs[tid + off]; rq[tid] += rq[tid + off]; }
        __syncthreads();
    }
    if (tid == 0) {
        float mean = rs[0] / n;
        float var = rq[0] / n - mean * mean;
        float inv = rsqrtf(var + EPSV);
        float gg = mode ? g[s] : g[c];
        float bb = mode ? be[s] : be[c];
        scale[cs] = gg * inv;
        shift[cs] = bb - mean * gg * inv;
    }
}

// ---------------- BN apply in-place ----------------
template <int C, int HWs>
__global__ void bn_apply_k(float* __restrict__ h, const float* __restrict__ scale,
                           const float* __restrict__ shift) {
    int idx = blockIdx.x * 256 + threadIdx.x;
    if (idx >= BSv * C * HWs) return;
    int c = (idx / HWs) % C;
    int bs = idx / (HWs * C);
    int cs = c * Sv + (bs % Sv);
    h[idx] = h[idx] * scale[cs] + shift[cs];
}

// ---------------- generic 3x3 conv (offset convs), LDS row tile ----------------
template <int Cin, int Cout, int HH, int WW, int WG>
__global__ void conv3x3_k(const float* __restrict__ in, const float* __restrict__ w,
                          const float* __restrict__ b, float* __restrict__ out) {
    int bs = blockIdx.x / HH;
    int h = blockIdx.x % HH;
    __shared__ __align__(16) float tile[Cin][3][WW + 2];
    int tid = threadIdx.x;
    for (int e = tid; e < Cin * 3 * (WW + 2); e += 256) {
        int col = e % (WW + 2);
        int r = (e / (WW + 2)) % 3;
        int c = e / (3 * (WW + 2));
        int y = h - 1 + r, xx = col - 1;
        float v = 0.f;
        if (y >= 0 && y < HH && xx >= 0 && xx < WW)
            v = in[((size_t)bs * Cin + c) * (HH * WW) + y * WW + xx];
        tile[c][r][col] = v;
    }
    __syncthreads();
    constexpr int NW = WW / WG;
    for (int e = tid; e < Cout * NW; e += 256) {
        int oc = e / NW;
        int wb = (e % NW) * WG;
        float acc[WG];
#pragma unroll
        for (int p = 0; p < WG; p++) acc[p] = b[oc];
        for (int c = 0; c < Cin; c++) {
            const float* wpc = w + ((size_t)oc * Cin + c) * 9;
#pragma unroll
            for (int r = 0; r < 3; r++) {
                float v[WG + 2];
#pragma unroll
                for (int q = 0; q < WG + 2; q++) v[q] = tile[c][r][wb + q];
#pragma unroll
                for (int kj = 0; kj < 3; kj++) {
                    float wk = wpc[r * 3 + kj];
#pragma unroll
                    for (int p = 0; p < WG; p++) acc[p] += v[p + kj] * wk;
                }
            }
        }
#pragma unroll
        for (int p = 0; p < WG; p++)
            out[((size_t)bs * Cout + oc) * (HH * WW) + h * WW + wb + p] = acc[p];
    }
}

// ---------------- weight transpose: w[o][ck] -> wt[ck][o] ----------------
__global__ void transpose_w_k(const float* __restrict__ w, float* __restrict__ wt,
                              int O, int CK) {
    int idx = blockIdx.x * 256 + threadIdx.x;
    if (idx >= O * CK) return;
    int o = idx / CK, ck = idx % CK;
    wt[(size_t)ck * O + o] = w[idx];
}

// ---------------- deformable conv, dg=2, per-(bs,row) block ----------------
// phase 1: bilinear-sample cols (transposed, j-major) into LDS (one d-half at a time)
// phase 2: 4o x 4px register-tiled dot against pre-transposed weights
template <int Cg, int O, int HH, int WW, int WP, bool RELU>
__global__ void deform_k(const float* __restrict__ in, const float* __restrict__ off,
                         const float* __restrict__ wtt, const float* __restrict__ bias,
                         float* __restrict__ out) {
    constexpr int C = 2 * Cg;
    constexpr int JH = Cg * 9;       // j per d-half
    constexpr int OG = O / 4;        // o-groups of 4
    constexpr int PQ = 256 / OG;     // px-groups of 4
    __shared__ __align__(16) float cols[JH * WP];
    int bs = blockIdx.x / HH;
    int h = blockIdx.x % HH;
    int tid = threadIdx.x;
    int og = tid % OG;
    int pq = tid / OG;
    bool active = (pq * 4 < WW);

    float acc[4][4];
#pragma unroll
    for (int i = 0; i < 4; i++)
#pragma unroll
        for (int p = 0; p < 4; p++) acc[i][p] = 0.f;

    for (int d = 0; d < 2; d++) {
        __syncthreads();
        // ---- fill ----
        for (int e = tid; e < WW * 9; e += 256) {
            int px = e / 9;
            int k = e % 9;
            int offc = (d * 9 + k) * 2;
            float oy = off[((size_t)bs * 36 + offc) * (HH * WW) + h * WW + px];
            float ox = off[((size_t)bs * 36 + offc + 1) * (HH * WW) + h * WW + px];
            float y = oy + (float)(h - 1) + (float)(k / 3);
            float x = ox + (float)(px - 1) + (float)(k % 3);
            float y0 = floorf(y), x0 = floorf(x);
            float wy1 = y - y0, wx1 = x - x0;
            float wy0 = 1.f - wy1, wx0 = 1.f - wx1;
            float yn1 = y0 + 1.f, xn1 = x0 + 1.f;
            bool vy0 = (y0 >= 0.f) && (y0 <= (float)(HH - 1));
            bool vy1 = (yn1 >= 0.f) && (yn1 <= (float)(HH - 1));
            bool vx0 = (x0 >= 0.f) && (x0 <= (float)(WW - 1));
            bool vx1 = (xn1 >= 0.f) && (xn1 <= (float)(WW - 1));
            int iy0 = min(max((int)y0, 0), HH - 1);
            int iy1 = min(max((int)yn1, 0), HH - 1);
            int ix0 = min(max((int)x0, 0), WW - 1);
            int ix1 = min(max((int)xn1, 0), WW - 1);
            float w00 = (vy0 && vx0) ? wy0 * wx0 : 0.f;
            float w01 = (vy0 && vx1) ? wy0 * wx1 : 0.f;
            float w10 = (vy1 && vx0) ? wy1 * wx0 : 0.f;
            float w11 = (vy1 && vx1) ? wy1 * wx1 : 0.f;
            int a00 = iy0 * WW + ix0, a01 = iy0 * WW + ix1;
            int a10 = iy1 * WW + ix0, a11 = iy1 * WW + ix1;
            const float* ip = in + ((size_t)bs * C + d * Cg) * (HH * WW);
            for (int cg = 0; cg < Cg; cg++) {
                float v = w00 * ip[a00] + w01 * ip[a01] + w10 * ip[a10] + w11 * ip[a11];
                cols[(cg * 9 + k) * WP + px] = v;
                ip += HH * WW;
            }
        }
        __syncthreads();
        // ---- accumulate ----
        if (active) {
            const float* wp = wtt + (size_t)d * JH * O + og * 4;
            for (int j = 0; j < JH; j++) {
                float4 wv = *(const float4*)(wp + (size_t)j * O);
                float4 cv = *(const float4*)(cols + j * WP + pq * 4);
                acc[0][0] += wv.x * cv.x; acc[0][1] += wv.x * cv.y;
                acc[0][2] += wv.x * cv.z; acc[0][3] += wv.x * cv.w;
                acc[1][0] += wv.y * cv.x; acc[1][1] += wv.y * cv.y;
                acc[1][2] += wv.y * cv.z; acc[1][3] += wv.y * cv.w;
                acc[2][0] += wv.z * cv.x; acc[2][1] += wv.z * cv.y;
                acc[2][2] += wv.z * cv.z; acc[2][3] += wv.z * cv.w;
                acc[3][0] += wv.w * cv.x; acc[3][1] += wv.w * cv.y;
                acc[3][2] += wv.w * cv.z; acc[3][3] += wv.w * cv.w;
            }
        }
    }
    if (active) {
#pragma unroll
        for (int i = 0; i < 4; i++) {
            int o = og * 4 + i;
            float bv = bias[o];
#pragma unroll
            for (int p = 0; p < 4; p++) {
                int px = pq * 4 + p;
                if (px < WW) {
                    float v = acc[i][p] + bv;
                    if (RELU) v = fmaxf(v, 0.f);
                    out[((size_t)bs * O + o) * (HH * WW) + h * WW + px] = v;
                }
            }
        }
    }
}

// ---------------- BN apply + 2x2 maxpool ----------------
template <int C, int HH, bool EMB>
__global__ void bn_pool_k(const float* __restrict__ in, const float* __restrict__ scale,
                          const float* __restrict__ shift, float* __restrict__ out) {
    constexpr int WO = HH / 2;
    int idx = blockIdx.x * 256 + threadIdx.x;
    if (idx >= BSv * C * WO * WO) return;
    int p = idx % (WO * WO);
    int c = (idx / (WO * WO)) % C;
    int bs = idx / (WO * WO * C);
    int ho = p / WO, wo = p % WO;
    int s = bs % Sv;
    int cs = c * Sv + s;
    float sc = scale[cs], sh = shift[cs];
    const float* ip = in + ((size_t)bs * C + c) * (HH * HH);
    float m = -INFINITY;
#pragma unroll
    for (int dy = 0; dy < 2; dy++)
#pragma unroll
        for (int dx = 0; dx < 2; dx++) {
            float v = ip[(2 * ho + dy) * HH + (2 * wo + dx)] * sc + sh;
            m = fmaxf(m, v);
        }
    if (EMB) {
        int b = bs / Sv;
        out[(((size_t)b * C + c) * Sv + s) * (WO * WO) + p] = m;
    } else {
        out[idx] = m;
    }
}

// ---------------- max over s + relu ----------------
__global__ void pool_s_relu_k(const float* __restrict__ emb, float* __restrict__ pool) {
    int idx = blockIdx.x * 256 + threadIdx.x;  // (b, c, p49)
    if (idx >= Bv * C3 * 49) return;
    int p = idx % 49;
    int c = (idx / 49) % C3;
    int b = idx / (49 * C3);
    float m = -INFINITY;
#pragma unroll
    for (int s = 0; s < Sv; s++)
        m = fmaxf(m, emb[(((size_t)b * C3 + c) * Sv + s) * 49 + p]);
    pool[idx] = fmaxf(m, 0.f);
}

// ---------------- fc: one block per (b,o) ----------------
__global__ void fc_k(const float* __restrict__ pool, const float* __restrict__ fw,
                     const float* __restrict__ fb, float* __restrict__ outL) {
    int b = blockIdx.x / 10, o = blockIdx.x % 10;
    int tid = threadIdx.x;
    float sum = 0.f;
    const float* pp = pool + (size_t)b * 12544;
    const float* wp = fw + (size_t)o * 12544;
    for (int i = tid; i < 12544; i += 256) sum += pp[i] * wp[i];
    __shared__ float red[256];
    red[tid] = sum;
    __syncthreads();
    for (int off = 128; off > 0; off >>= 1) {
        if (tid < off) red[tid] += red[tid + off];
        __syncthreads();
    }
    if (tid == 0) outL[b * 10 + o] = red[0] + fb[o];
}

extern "C" void kernel_launch(void* const* d_in, const int* in_sizes, int n_in,
                              void* d_out, int out_size, void* d_ws, size_t ws_size,
                              hipStream_t stream) {
    const float* x       = (const float*)d_in[0];
    const float* conv1_w = (const float*)d_in[1];
    const float* conv1_b = (const float*)d_in[2];
    const float* off1_w  = (const float*)d_in[3];
    const float* off1_b  = (const float*)d_in[4];
    const float* d1_w    = (const float*)d_in[5];
    const float* d1_b    = (const float*)d_in[6];
    const float* off2_w  = (const float*)d_in[7];
    const float* off2_b  = (const float*)d_in[8];
    const float* d2_w    = (const float*)d_in[9];
    const float* d2_b    = (const float*)d_in[10];
    const float* bn1_g   = (const float*)d_in[11];
    const float* bn1_b   = (const float*)d_in[12];
    const float* bn2_g   = (const float*)d_in[13];
    const float* bn2_b   = (const float*)d_in[14];
    const float* bn3_g   = (const float*)d_in[15];
    const float* bn3_b   = (const float*)d_in[16];
    const float* fc_w    = (const float*)d_in[17];
    const float* fc_b    = (const float*)d_in[18];
    float* outp = (float*)d_out;

    float* ws = (float*)d_ws;
    float* h1   = ws;                    // 12,845,056 (reused as h3)
    float* offb = h1 + 12845056;         // 7,225,344 (off1, reused as off2)
    float* h2   = offb + 7225344;        // 25,690,112
    float* h2p  = h2 + 25690112;         // 6,422,528
    float* pool = h2p + 6422528;         // 802,816
    float* stats = pool + 802816;        // 8192
    float* scale = stats;
    float* shift = stats + 4096;
    float* wt1  = stats + 8192;          // 73,728
    float* wt2  = wt1 + 73728;           // 294,912

    float* emb = outp + 640;

    // stage 1: conv1 + relu
    conv1_relu_k<<<50176, 256, 0, stream>>>(x, conv1_w, conv1_b, h1);
    // bn1 (gamma per c)
    bn_stats_k<64, 784><<<256, 256, 0, stream>>>(h1, bn1_g, bn1_b, 0, scale, shift);
    bn_apply_k<64, 784><<<50176, 256, 0, stream>>>(h1, scale, shift);
    // offset1 conv
    conv3x3_k<64, 36, 28, 28, 4><<<7168, 256, 0, stream>>>(h1, off1_w, off1_b, offb);
    // deform1
    transpose_w_k<<<288, 256, 0, stream>>>(d1_w, wt1, 128, 576);
    deform_k<32, 128, 28, 28, 28, true><<<7168, 256, 0, stream>>>(h1, offb, wt1, d1_b, h2);
    // bn2 (gamma per s) + pool
    bn_stats_k<128, 784><<<512, 256, 0, stream>>>(h2, bn2_g, bn2_b, 1, scale, shift);
    bn_pool_k<128, 28, false><<<25088, 256, 0, stream>>>(h2, scale, shift, h2p);
    // offset2 conv
    conv3x3_k<128, 36, 14, 14, 2><<<3584, 256, 0, stream>>>(h2p, off2_w, off2_b, offb);
    // deform2
    transpose_w_k<<<1152, 256, 0, stream>>>(d2_w, wt2, 256, 1152);
    deform_k<64, 256, 14, 14, 16, false><<<3584, 256, 0, stream>>>(h2p, offb, wt2, d2_b, h1);
    // bn3 (gamma per s) + pool -> embedding (b,c,s,7,7) directly into d_out
    bn_stats_k<256, 196><<<1024, 256, 0, stream>>>(h1, bn3_g, bn3_b, 1, scale, shift);
    bn_pool_k<256, 14, true><<<12544, 256, 0, stream>>>(h1, scale, shift, emb);
    // head
    pool_s_relu_k<<<3136, 256, 0, stream>>>(emb, pool);
    fc_k<<<640, 256, 0, stream>>>(pool, fc_w, fc_b, outp);
}